// Round 21
// baseline (294.776 us; speedup 1.0000x reference)
//
#include <hip/hip_runtime.h>
#include <hip/hip_bf16.h>

#define N_ROWS 16384
#define D 128
#define KVTILE 32
#define NSPLIT 4
#define KV_PER_SPLIT (N_ROWS / NSPLIT)     // 4096
#define NT (KV_PER_SPLIT / KVTILE)         // 128
#define NTILES (N_ROWS / KVTILE)           // 512
#define LOG2E 1.4426950408889634f
#define SCALE 1.0f
#define LN_EPS 1e-5f
#define L2_EPS 1e-12f

typedef float f32x4 __attribute__((ext_vector_type(4)));
typedef short s16x8 __attribute__((ext_vector_type(8)));
typedef unsigned short u16;

__device__ __forceinline__ u16 f2bf(float f) {
    union { float f; unsigned u; } v; v.f = f;
    unsigned r = v.u + 0x7FFFu + ((v.u >> 16) & 1u);   // RNE
    return (u16)(r >> 16);
}
__device__ __forceinline__ unsigned pk2(float lo, float hi) {
    union { __hip_bfloat162 b; unsigned u; } c;
    c.b = __float22bfloat162_rn(float2{lo, hi});
    return c.u;
}
__device__ __forceinline__ float exp2_hw(float f) {
    return __builtin_amdgcn_exp2f(f);      // v_exp_f32 (base-2)
}

// ---------------- prep: invnrm[i] = 1 / max(||x_i||, eps) ----------------
__global__ __launch_bounds__(256) void prep_norms(const float* __restrict__ x,
                                                  float* __restrict__ invnrm) {
    int t = threadIdx.x;
    int row = blockIdx.x * 64 + (t >> 2);
    int q = t & 3;
    const float4* xr = (const float4*)(x + (size_t)row * D);
    float s = 0.f;
#pragma unroll
    for (int i = 0; i < 8; ++i) {
        float4 v = xr[q * 8 + i];
        s += v.x * v.x + v.y * v.y + v.z * v.z + v.w * v.w;
    }
    s += __shfl_xor(s, 1);
    s += __shfl_xor(s, 2);
    if (q == 0) invnrm[row] = 1.0f / fmaxf(sqrtf(s), L2_EPS);
}

// Kimg per 32-kv tile (8 KB, 512 chunks of 16B), ordered for 16x16x32 A-frags:
// chunk ci = (hh*4+ks)*64 + 16*g + c holds bf16(xn[32*tile+16*hh+c][32*ks+8*g+e]),
// e=0..7, xn = x*invnrm.  (A-frag: row=c=kv, k=8g+e=d-within-32)
__global__ __launch_bounds__(256) void prep_imgK(const float* __restrict__ x,
                                                 const float* __restrict__ invnrm,
                                                 u16* __restrict__ Kimg) {
    int cix = blockIdx.x * 256 + threadIdx.x;     // 0..262143
    int tile = cix >> 9;
    int ci = cix & 511;
    int sub = ci >> 6;                            // hh*4+ks
    int hh = sub >> 2, ks = sub & 3;
    int g = (ci >> 4) & 3, c = ci & 15;
    int kv = 32 * tile + 16 * hh + c;
    const float* p = x + (size_t)kv * D + 32 * ks + 8 * g;
    float inv = invnrm[kv];
    float4 a = *(const float4*)p;
    float4 b = *(const float4*)(p + 4);
    union { unsigned u[4]; s16x8 v; } pk;
    pk.u[0] = pk2(a.x * inv, a.y * inv);
    pk.u[1] = pk2(a.z * inv, a.w * inv);
    pk.u[2] = pk2(b.x * inv, b.y * inv);
    pk.u[3] = pk2(b.z * inv, b.w * inv);
    *(s16x8*)(Kimg + (size_t)cix * 8) = pk.v;
}

// VTimg per 32-kv tile (8 KB): chunk ci = db*64 + 16*g + c holds V^T elements
// e=0..7: bf16(x[32*tile + 8*g + e][16*db + c]).  (A-frag for PV: row=c=d, k=8g+e=kv)
__global__ __launch_bounds__(256) void prep_imgVT(const float* __restrict__ x,
                                                  u16* __restrict__ VTimg) {
    __shared__ float sx[KVTILE][D + 4];
    int tile = blockIdx.x;
    int tid = threadIdx.x;
#pragma unroll
    for (int j = 0; j < 4; ++j) {
        int idx = j * 1024 + tid * 4;
        int r = idx >> 7, cc = idx & 127;
        *(float4*)&sx[r][cc] = *(const float4*)(x + (size_t)(tile * KVTILE + r) * D + cc);
    }
    __syncthreads();
#pragma unroll
    for (int j = 0; j < 2; ++j) {
        int ci = j * 256 + tid;                   // 0..511
        int db = ci >> 6;
        int g = (ci >> 4) & 3, c = ci & 15;
        int d = 16 * db + c;
        int kv0 = 8 * g;
        union { u16 s[8]; s16x8 v; } pk;
#pragma unroll
        for (int e = 0; e < 8; ++e) pk.s[e] = f2bf(sx[kv0 + e][d]);
        *(s16x8*)(VTimg + (size_t)tile * 4096 + (size_t)ci * 8) = pk.v;
    }
}

// 4 waves x 16 q-rows (16x16x32 MFMA); no LDS/barriers; K,V direct from L1/L2.
// <=128 regs/wave -> 4 waves/SIMD (m69 quantization) -> pipe overlap via TLP.
__global__ __launch_bounds__(256, 4) void attn(const float* __restrict__ x,
                                               const u16* __restrict__ Kimg,
                                               const u16* __restrict__ VTimg,
                                               const float* __restrict__ invnrm,
                                               float* __restrict__ num,
                                               float* __restrict__ denom) {
    const int bx = blockIdx.x;
    const int qb = bx >> 2;                 // 0..255
    const int sp = bx & 3;                  // split; XCDs x and x+4 share panel sp
    const int q0blk = qb * 64;
    const int tile0 = sp * NT;

    const int tid = threadIdx.x;
    const int w = tid >> 6;                 // 4 waves, 16 q-rows each
    const int lane = tid & 63;
    const int g = lane >> 4;                // 0..3
    const int c = lane & 15;

    const int q0w = q0blk + 16 * w;
    const int q = q0w + c;

    // --- Q B-fragments (col=c=q, k=8g+j within 32-step), scaled ---
    const float sc = invnrm[q] * LOG2E;
    s16x8 qf[4];
#pragma unroll
    for (int ks = 0; ks < 4; ++ks) {
        const float* p = x + (size_t)q * D + 32 * ks + 8 * g;
        float4 a = *(const float4*)p;
        float4 b = *(const float4*)(p + 4);
        union { unsigned u[4]; s16x8 v; } pk;
        pk.u[0] = pk2(a.x * sc, a.y * sc);
        pk.u[1] = pk2(a.z * sc, a.w * sc);
        pk.u[2] = pk2(b.x * sc, b.y * sc);
        pk.u[3] = pk2(b.z * sc, b.w * sc);
        qf[ks] = pk.v;
    }

    f32x4 acc[8];
#pragma unroll
    for (int db = 0; db < 8; ++db)
#pragma unroll
        for (int r = 0; r < 4; ++r) acc[db][r] = 0.f;
    float rowsum = 0.f;

    const s16x8* ktp = (const s16x8*)Kimg + (size_t)tile0 * 512 + lane;
    const s16x8* vtp = (const s16x8*)VTimg + (size_t)tile0 * 512 + lane;

    for (int tile = 0; tile < NT; ++tile) {
        // ---- K fragments (8 coalesced 1KB wave-reads) ----
        s16x8 kf[8];
#pragma unroll
        for (int j = 0; j < 8; ++j) kf[j] = ktp[64 * j];
        ktp += 512;

        // ---- S^T = K Qn^T: two kv-halves, K=32 steps over d=128 ----
        f32x4 s0, s1;
#pragma unroll
        for (int r = 0; r < 4; ++r) { s0[r] = 0.f; s1[r] = 0.f; }
        __builtin_amdgcn_s_setprio(1);
#pragma unroll
        for (int ks = 0; ks < 4; ++ks) {
            s0 = __builtin_amdgcn_mfma_f32_16x16x32_bf16(kf[ks], qf[ks], s0, 0, 0, 0);
            s1 = __builtin_amdgcn_mfma_f32_16x16x32_bf16(kf[4 + ks], qf[ks], s1, 0, 0, 0);
        }
        __builtin_amdgcn_s_setprio(0);

        // ---- P = exp2(S^T); lane holds kv {4g+r, 16+4g+r} for q=c ----
        float p0[4], p1[4];
#pragma unroll
        for (int r = 0; r < 4; ++r) {
            p0[r] = exp2_hw(s0[r]);
            p1[r] = exp2_hw(s1[r]);
            rowsum += p0[r] + p1[r];
        }
        unsigned A0[2] = {pk2(p0[0], p0[1]), pk2(p0[2], p0[3])};
        unsigned A1[2] = {pk2(p1[0], p1[1]), pk2(p1[2], p1[3])};

        // ---- exchange to PV B-frag: lane needs P[kv=8g+j][q=c] ----
        unsigned B0[2], B1[2], y[2];
#pragma unroll
        for (int m = 0; m < 2; ++m) {
            B0[m] = (unsigned)__shfl_xor((int)A0[m], 32);
            B1[m] = (unsigned)__shfl_xor((int)A1[m], 32);
        }
#pragma unroll
        for (int m = 0; m < 2; ++m) {
            unsigned xm = (g & 1) ? ((g & 2) ? B1[m] : A0[m])
                                  : ((g & 2) ? A1[m] : B0[m]);
            y[m] = (unsigned)__shfl_xor((int)xm, 16);
        }
        union { unsigned u[4]; s16x8 v; } Pv;
#pragma unroll
        for (int m = 0; m < 2; ++m) {
            Pv.u[m]     = (g == 0) ? A0[m] : (g == 2) ? B1[m] : y[m];
            Pv.u[2 + m] = (g == 1) ? B0[m] : (g == 3) ? A1[m] : y[m];
        }

        // ---- O^T += V^T P  (A=V^T frag, B=P frag, K=32 kv) ----
        __builtin_amdgcn_s_setprio(1);
#pragma unroll
        for (int db = 0; db < 8; ++db) {
            s16x8 vf = vtp[64 * db];
            acc[db] = __builtin_amdgcn_mfma_f32_16x16x32_bf16(vf, Pv.v, acc[db], 0, 0, 0);
        }
        __builtin_amdgcn_s_setprio(0);
        vtp += 512;
    }

    // ---- epilogue ----
    float tot = rowsum;
    tot += __shfl_xor(tot, 16);
    tot += __shfl_xor(tot, 32);
    if (lane < 16) atomicAdd(&denom[q0w + c], tot);

    // transpose O^T (d=16db+4g+r, q=c) -> O rows, then coalesced atomics:
    // target lane (g,c) reg r = acc-elem at src lane 16*(c>>2)+4g+r, src reg c&3.
#pragma unroll
    for (int db = 0; db < 8; ++db) {
#pragma unroll
        for (int r = 0; r < 4; ++r) {
            int srcl = 16 * (c >> 2) + 4 * g + r;
            float t0 = __shfl(acc[db][0], srcl);
            float t1 = __shfl(acc[db][1], srcl);
            float t2 = __shfl(acc[db][2], srcl);
            float t3 = __shfl(acc[db][3], srcl);
            int sel = c & 3;
            float tv = (sel == 0) ? t0 : (sel == 1) ? t1 : (sel == 2) ? t2 : t3;
            atomicAdd(&num[(size_t)(q0w + 4 * g + r) * D + 16 * db + c], tv);
        }
    }
}

// ---------------- finalize: y = 2x - num/denom ; LayerNorm ----------------
__global__ __launch_bounds__(256) void finalize(const float* __restrict__ x,
                                                const float* __restrict__ gamma,
                                                const float* __restrict__ beta,
                                                const float* __restrict__ denom,
                                                float* __restrict__ out) {  // out == num, in place
    int t = threadIdx.x;
    int row = blockIdx.x * 64 + (t >> 2);
    int q = t & 3;
    float invd = 1.0f / denom[row];
    const float4* xr = (const float4*)(x + (size_t)row * D);
    const float4* nr = (const float4*)(out + (size_t)row * D);
    float y[32];
    float s1 = 0.f, s2 = 0.f;
#pragma unroll
    for (int i = 0; i < 8; ++i) {
        float4 xv = xr[q * 8 + i];
        float4 nv = nr[q * 8 + i];
#pragma unroll
        for (int j = 0; j < 4; ++j) {
            float yv = (1.0f + SCALE) * (&xv.x)[j] - SCALE * ((&nv.x)[j] * invd);
            y[i * 4 + j] = yv;
            s1 += yv;
            s2 += yv * yv;
        }
    }
    s1 += __shfl_xor(s1, 1); s1 += __shfl_xor(s1, 2);
    s2 += __shfl_xor(s2, 1); s2 += __shfl_xor(s2, 2);
    float mu = s1 * (1.0f / D);
    float var = s2 * (1.0f / D) - mu * mu;
    float rstd = rsqrtf(var + LN_EPS);
    float4* orow = (float4*)(out + (size_t)row * D);
#pragma unroll
    for (int i = 0; i < 8; ++i) {
        int c = q * 32 + i * 4;
        float4 o;
#pragma unroll
        for (int j = 0; j < 4; ++j)
            (&o.x)[j] = (y[i * 4 + j] - mu) * rstd * gamma[c + j] + beta[c + j];
        orow[q * 8 + i] = o;
    }
}

extern "C" void kernel_launch(void* const* d_in, const int* in_sizes, int n_in,
                              void* d_out, int out_size, void* d_ws, size_t ws_size,
                              hipStream_t stream) {
    const float* x = (const float*)d_in[0];
    const float* gamma = (const float*)d_in[1];
    const float* beta = (const float*)d_in[2];
    float* out = (float*)d_out;

    float* invnrm = (float*)d_ws;                       // 64 KB
    float* denom = invnrm + N_ROWS;                     // 64 KB
    u16* Kimg = (u16*)(denom + N_ROWS);                 // 4 MB
    u16* VTimg = Kimg + (size_t)N_ROWS * D;             // 4 MB  (total ~8.4 MB)

    (void)hipMemsetAsync(d_out, 0, (size_t)N_ROWS * D * sizeof(float), stream);  // num accumulator
    (void)hipMemsetAsync(denom, 0, (size_t)N_ROWS * sizeof(float), stream);

    prep_norms<<<N_ROWS / 64, 256, 0, stream>>>(x, invnrm);
    prep_imgK<<<NTILES * 2, 256, 0, stream>>>(x, invnrm, Kimg);
    prep_imgVT<<<NTILES, 256, 0, stream>>>(x, VTimg);
    attn<<<(N_ROWS / 64) * NSPLIT, 256, 0, stream>>>(x, Kimg, VTimg, invnrm, out, denom);
    finalize<<<N_ROWS / 64, 256, 0, stream>>>(x, gamma, beta, denom, out);
}